// Round 2
// baseline (741.759 us; speedup 1.0000x reference)
//
#include <hip/hip_runtime.h>
#include <hip/hip_bf16.h>

#define N_GRAPHS 64
#define IN_FEATS 64
#define HIDDEN 32
#define OUT_DIM 2

// t1 = node_feats(f32 [N,64]) @ W1(f32 [64,32]) -> f32 [N,32]   (bias deferred)
__global__ void k_lin1(const float* __restrict__ nf,
                       const float* __restrict__ W,
                       float* __restrict__ out, int n) {
    __shared__ float w[IN_FEATS * HIDDEN];
    for (int i = threadIdx.x; i < IN_FEATS * HIDDEN; i += blockDim.x)
        w[i] = W[i];
    __syncthreads();
    int row = blockIdx.x * blockDim.x + threadIdx.x;
    if (row >= n) return;

    float a[IN_FEATS];
    const float4* r4 = reinterpret_cast<const float4*>(nf + (long long)row * IN_FEATS);
    #pragma unroll
    for (int v = 0; v < IN_FEATS / 4; v++) {
        float4 q = r4[v];
        a[v * 4 + 0] = q.x; a[v * 4 + 1] = q.y; a[v * 4 + 2] = q.z; a[v * 4 + 3] = q.w;
    }
    float acc[HIDDEN];
    #pragma unroll
    for (int f = 0; f < HIDDEN; f++) acc[f] = 0.f;
    for (int k = 0; k < IN_FEATS; k++) {
        float av = a[k];
        #pragma unroll
        for (int f = 0; f < HIDDEN; f++) acc[f] += av * w[k * HIDDEN + f];
    }
    float* o = out + (long long)row * HIDDEN;
    #pragma unroll
    for (int f = 0; f < HIDDEN; f++) o[f] = acc[f];
}

// t = (agg(f32 [N,32]) + b[32]) @ W(f32 [32,32]) -> f32 [N,32]
__global__ void k_lin2(const float* __restrict__ in,
                       const float* __restrict__ b,
                       const float* __restrict__ W,
                       float* __restrict__ out, int n) {
    __shared__ float w[HIDDEN * HIDDEN];
    __shared__ float bs[HIDDEN];
    for (int i = threadIdx.x; i < HIDDEN * HIDDEN; i += blockDim.x) w[i] = W[i];
    if (threadIdx.x < HIDDEN) bs[threadIdx.x] = b[threadIdx.x];
    __syncthreads();
    int row = blockIdx.x * blockDim.x + threadIdx.x;
    if (row >= n) return;

    float a[HIDDEN];
    const float4* r4 = reinterpret_cast<const float4*>(in + (long long)row * HIDDEN);
    #pragma unroll
    for (int v = 0; v < HIDDEN / 4; v++) {
        float4 q = r4[v];
        a[v * 4 + 0] = q.x; a[v * 4 + 1] = q.y; a[v * 4 + 2] = q.z; a[v * 4 + 3] = q.w;
    }
    #pragma unroll
    for (int k = 0; k < HIDDEN; k++) a[k] += bs[k];
    float acc[HIDDEN];
    #pragma unroll
    for (int f = 0; f < HIDDEN; f++) acc[f] = 0.f;
    for (int k = 0; k < HIDDEN; k++) {
        float av = a[k];
        #pragma unroll
        for (int f = 0; f < HIDDEN; f++) acc[f] += av * w[k * HIDDEN + f];
    }
    float* o = out + (long long)row * HIDDEN;
    #pragma unroll
    for (int f = 0; f < HIDDEN; f++) o[f] = acc[f];
}

// t3 = (agg2 + b2) @ W3(f32 [32,2]) -> f32 [N,2]
__global__ void k_lin3(const float* __restrict__ in,
                       const float* __restrict__ b,
                       const float* __restrict__ W,
                       float* __restrict__ out, int n) {
    __shared__ float w[HIDDEN * OUT_DIM];
    __shared__ float bs[HIDDEN];
    for (int i = threadIdx.x; i < HIDDEN * OUT_DIM; i += blockDim.x) w[i] = W[i];
    if (threadIdx.x < HIDDEN) bs[threadIdx.x] = b[threadIdx.x];
    __syncthreads();
    int row = blockIdx.x * blockDim.x + threadIdx.x;
    if (row >= n) return;

    const float4* r4 = reinterpret_cast<const float4*>(in + (long long)row * HIDDEN);
    float acc0 = 0.f, acc1 = 0.f;
    #pragma unroll
    for (int v = 0; v < HIDDEN / 4; v++) {
        float4 q = r4[v];
        float av;
        av = q.x + bs[v * 4 + 0]; acc0 += av * w[(v * 4 + 0) * 2]; acc1 += av * w[(v * 4 + 0) * 2 + 1];
        av = q.y + bs[v * 4 + 1]; acc0 += av * w[(v * 4 + 1) * 2]; acc1 += av * w[(v * 4 + 1) * 2 + 1];
        av = q.z + bs[v * 4 + 2]; acc0 += av * w[(v * 4 + 2) * 2]; acc1 += av * w[(v * 4 + 2) * 2 + 1];
        av = q.w + bs[v * 4 + 3]; acc0 += av * w[(v * 4 + 3) * 2]; acc1 += av * w[(v * 4 + 3) * 2 + 1];
    }
    float2* o = reinterpret_cast<float2*>(out + (long long)row * OUT_DIM);
    *o = make_float2(acc0, acc1);
}

// scatter-add: agg[dst[e]][f] += t[src[e]][f]
template <int F>
__global__ void k_scatter(const float* __restrict__ t,
                          const int* __restrict__ src,
                          const int* __restrict__ dst,
                          float* __restrict__ agg, int n_edges) {
    unsigned int tid = blockIdx.x * blockDim.x + threadIdx.x;
    unsigned int e = tid / F;
    unsigned int f = tid % F;
    if (e >= (unsigned int)n_edges) return;
    int s = src[e];
    int d = dst[e];
    atomicAdd(agg + (long long)d * F + f, t[(long long)s * F + f]);
}

// h3 = agg3 + b3 -> f32 d_out[64:]
__global__ void k_out(const float* __restrict__ agg3,
                      const float* __restrict__ b3,
                      float* __restrict__ out, int n2) {
    int tid = blockIdx.x * blockDim.x + threadIdx.x;
    if (tid >= n2) return;
    out[tid] = agg3[tid] + b3[tid & 1];
}

// start[g] = lower_bound(graph_ids, g) for g in [0,64]
__global__ void k_bounds(const int* __restrict__ gids, int n, int* __restrict__ start) {
    int g = threadIdx.x;
    if (g > N_GRAPHS) return;
    int lo = 0, hi = n;
    while (lo < hi) {
        int mid = (lo + hi) >> 1;
        if (gids[mid] < g) lo = mid + 1; else hi = mid;
    }
    start[g] = lo;
}

// per-graph mean of original node features -> ge f32 [64,64]
__global__ void k_gsum(const float* __restrict__ nf,
                       const int* __restrict__ start,
                       float* __restrict__ ge) {
    int g = blockIdx.x;
    int s = start[g], e = start[g + 1];
    int f = threadIdx.x & 63;
    int sub = threadIdx.x >> 6;  // 0..3
    float acc = 0.f;
    for (int i = s + sub; i < e; i += 4)
        acc += nf[(long long)i * IN_FEATS + f];
    __shared__ float red[256];
    red[threadIdx.x] = acc;
    __syncthreads();
    if (threadIdx.x < 64) {
        float v = red[threadIdx.x] + red[threadIdx.x + 64] +
                  red[threadIdx.x + 128] + red[threadIdx.x + 192];
        float cnt = (float)(e - s);
        ge[g * IN_FEATS + threadIdx.x] = v / fmaxf(cnt, 1.0f);
    }
}

// prediction = sigmoid(ge @ Wl + bl) -> f32 d_out[0:64]
__global__ void k_pred(const float* __restrict__ ge,
                       const float* __restrict__ Wl,
                       const float* __restrict__ bl,
                       float* __restrict__ out) {
    int g = threadIdx.x;
    if (g >= N_GRAPHS) return;
    float acc = bl[0];
    for (int k = 0; k < IN_FEATS; k++)
        acc += ge[g * IN_FEATS + k] * Wl[k];
    float s = 1.f / (1.f + expf(-acc));
    out[g] = s;
}

extern "C" void kernel_launch(void* const* d_in, const int* in_sizes, int n_in,
                              void* d_out, int out_size, void* d_ws, size_t ws_size,
                              hipStream_t stream) {
    const float* nf = (const float*)d_in[0];   // node_feats f32 [N,64]
    // d_in[1] edge_feats: unused by the reference
    const float* W1 = (const float*)d_in[2];   // [64,32]
    const float* b1 = (const float*)d_in[3];   // [32]
    const float* W2 = (const float*)d_in[4];   // [32,32]
    const float* b2 = (const float*)d_in[5];   // [32]
    const float* W3 = (const float*)d_in[6];   // [32,2]
    const float* b3 = (const float*)d_in[7];   // [2]
    const float* Wl = (const float*)d_in[8];   // [64,1]
    const float* bl = (const float*)d_in[9];   // [1]
    const int* src  = (const int*)d_in[10];
    const int* dst  = (const int*)d_in[11];
    const int* gids = (const int*)d_in[12];

    const int N = in_sizes[0] / IN_FEATS;     // 100000
    const int E = in_sizes[10];               // 1600000

    float* out = (float*)d_out;

    // workspace layout (f32): 2*N*32 + 2*N*2 + 64*64 + 65 floats ≈ 27.2 MB
    float* bufA = (float*)d_ws;               // t        [N,32]
    float* bufB = bufA + (size_t)N * HIDDEN;  // agg      [N,32]
    float* bufC = bufB + (size_t)N * HIDDEN;  // t3       [N,2]
    float* bufD = bufC + (size_t)N * OUT_DIM; // agg3     [N,2]
    float* ge   = bufD + (size_t)N * OUT_DIM; // [64,64]
    int* start  = (int*)(ge + N_GRAPHS * IN_FEATS); // [65]

    const int TB = 256;
    int nodeBlocks = (N + TB - 1) / TB;
    unsigned int scat32Blocks = ((unsigned int)E * HIDDEN + TB - 1) / TB;
    unsigned int scat2Blocks  = ((unsigned int)E * OUT_DIM + TB - 1) / TB;

    // ---- layer 1: t1 = nf @ W1 ; agg1 = scatter(t1) ----
    k_lin1<<<nodeBlocks, TB, 0, stream>>>(nf, W1, bufA, N);
    hipMemsetAsync(bufB, 0, (size_t)N * HIDDEN * sizeof(float), stream);
    k_scatter<HIDDEN><<<scat32Blocks, TB, 0, stream>>>(bufA, src, dst, bufB, E);

    // ---- layer 2: t2 = (agg1+b1) @ W2 ; agg2 = scatter(t2) ----
    k_lin2<<<nodeBlocks, TB, 0, stream>>>(bufB, b1, W2, bufA, N);
    hipMemsetAsync(bufB, 0, (size_t)N * HIDDEN * sizeof(float), stream);
    k_scatter<HIDDEN><<<scat32Blocks, TB, 0, stream>>>(bufA, src, dst, bufB, E);

    // ---- layer 3: t3 = (agg2+b2) @ W3 ; agg3 = scatter(t3) ; h3 = agg3+b3 ----
    k_lin3<<<nodeBlocks, TB, 0, stream>>>(bufB, b2, W3, bufC, N);
    hipMemsetAsync(bufD, 0, (size_t)N * OUT_DIM * sizeof(float), stream);
    k_scatter<OUT_DIM><<<scat2Blocks, TB, 0, stream>>>(bufC, src, dst, bufD, E);
    k_out<<<(N * OUT_DIM + TB - 1) / TB, TB, 0, stream>>>(bufD, b3, out + N_GRAPHS, N * OUT_DIM);

    // ---- graph embedding + prediction ----
    k_bounds<<<1, 128, 0, stream>>>(gids, N, start);
    k_gsum<<<N_GRAPHS, 256, 0, stream>>>(nf, start, ge);
    k_pred<<<1, 64, 0, stream>>>(ge, Wl, bl, out);
}

// Round 3
// 626.680 us; speedup vs baseline: 1.1836x; 1.1836x over previous
//
#include <hip/hip_runtime.h>
#include <hip/hip_bf16.h>

#define N_GRAPHS 64
#define IN_FEATS 64
#define HIDDEN 32
#define OUT_DIM 2
#define CHUNK 1024

// t1 = node_feats(f32 [N,64]) @ W1(f32 [64,32]) -> f32 [N,32]   (bias deferred)
__global__ void k_lin1(const float* __restrict__ nf,
                       const float* __restrict__ W,
                       float* __restrict__ out, int n) {
    __shared__ float w[IN_FEATS * HIDDEN];
    for (int i = threadIdx.x; i < IN_FEATS * HIDDEN; i += blockDim.x)
        w[i] = W[i];
    __syncthreads();
    int row = blockIdx.x * blockDim.x + threadIdx.x;
    if (row >= n) return;

    float a[IN_FEATS];
    const float4* r4 = reinterpret_cast<const float4*>(nf + (long long)row * IN_FEATS);
    #pragma unroll
    for (int v = 0; v < IN_FEATS / 4; v++) {
        float4 q = r4[v];
        a[v * 4 + 0] = q.x; a[v * 4 + 1] = q.y; a[v * 4 + 2] = q.z; a[v * 4 + 3] = q.w;
    }
    float acc[HIDDEN];
    #pragma unroll
    for (int f = 0; f < HIDDEN; f++) acc[f] = 0.f;
    for (int k = 0; k < IN_FEATS; k++) {
        float av = a[k];
        #pragma unroll
        for (int f = 0; f < HIDDEN; f++) acc[f] += av * w[k * HIDDEN + f];
    }
    float* o = out + (long long)row * HIDDEN;
    #pragma unroll
    for (int f = 0; f < HIDDEN; f++) o[f] = acc[f];
}

// t = (agg(f32 [N,32]) + b[32]) @ W(f32 [32,32]) -> f32 [N,32]
__global__ void k_lin2(const float* __restrict__ in,
                       const float* __restrict__ b,
                       const float* __restrict__ W,
                       float* __restrict__ out, int n) {
    __shared__ float w[HIDDEN * HIDDEN];
    __shared__ float bs[HIDDEN];
    for (int i = threadIdx.x; i < HIDDEN * HIDDEN; i += blockDim.x) w[i] = W[i];
    if (threadIdx.x < HIDDEN) bs[threadIdx.x] = b[threadIdx.x];
    __syncthreads();
    int row = blockIdx.x * blockDim.x + threadIdx.x;
    if (row >= n) return;

    float a[HIDDEN];
    const float4* r4 = reinterpret_cast<const float4*>(in + (long long)row * HIDDEN);
    #pragma unroll
    for (int v = 0; v < HIDDEN / 4; v++) {
        float4 q = r4[v];
        a[v * 4 + 0] = q.x; a[v * 4 + 1] = q.y; a[v * 4 + 2] = q.z; a[v * 4 + 3] = q.w;
    }
    #pragma unroll
    for (int k = 0; k < HIDDEN; k++) a[k] += bs[k];
    float acc[HIDDEN];
    #pragma unroll
    for (int f = 0; f < HIDDEN; f++) acc[f] = 0.f;
    for (int k = 0; k < HIDDEN; k++) {
        float av = a[k];
        #pragma unroll
        for (int f = 0; f < HIDDEN; f++) acc[f] += av * w[k * HIDDEN + f];
    }
    float* o = out + (long long)row * HIDDEN;
    #pragma unroll
    for (int f = 0; f < HIDDEN; f++) o[f] = acc[f];
}

// t3 = (agg2 + b2) @ W3(f32 [32,2]) -> f32 [N,2]
__global__ void k_lin3(const float* __restrict__ in,
                       const float* __restrict__ b,
                       const float* __restrict__ W,
                       float* __restrict__ out, int n) {
    __shared__ float w[HIDDEN * OUT_DIM];
    __shared__ float bs[HIDDEN];
    for (int i = threadIdx.x; i < HIDDEN * OUT_DIM; i += blockDim.x) w[i] = W[i];
    if (threadIdx.x < HIDDEN) bs[threadIdx.x] = b[threadIdx.x];
    __syncthreads();
    int row = blockIdx.x * blockDim.x + threadIdx.x;
    if (row >= n) return;

    const float4* r4 = reinterpret_cast<const float4*>(in + (long long)row * HIDDEN);
    float acc0 = 0.f, acc1 = 0.f;
    #pragma unroll
    for (int v = 0; v < HIDDEN / 4; v++) {
        float4 q = r4[v];
        float av;
        av = q.x + bs[v * 4 + 0]; acc0 += av * w[(v * 4 + 0) * 2]; acc1 += av * w[(v * 4 + 0) * 2 + 1];
        av = q.y + bs[v * 4 + 1]; acc0 += av * w[(v * 4 + 1) * 2]; acc1 += av * w[(v * 4 + 1) * 2 + 1];
        av = q.z + bs[v * 4 + 2]; acc0 += av * w[(v * 4 + 2) * 2]; acc1 += av * w[(v * 4 + 2) * 2 + 1];
        av = q.w + bs[v * 4 + 3]; acc0 += av * w[(v * 4 + 3) * 2]; acc1 += av * w[(v * 4 + 3) * 2 + 1];
    }
    float2* o = reinterpret_cast<float2*>(out + (long long)row * OUT_DIM);
    *o = make_float2(acc0, acc1);
}

// ---------------- CSR build (by dst) ----------------

__global__ void k_deg(const int* __restrict__ dst, int* __restrict__ deg, int E) {
    int e = blockIdx.x * blockDim.x + threadIdx.x;
    if (e < E) atomicAdd(&deg[dst[e]], 1);
}

// per-chunk sums of deg (CHUNK elems per block, 256 threads)
__global__ void k_chunksum(const int* __restrict__ deg, int* __restrict__ csum, int n) {
    __shared__ int sh[256];
    int c0 = blockIdx.x * CHUNK;
    int t = threadIdx.x;
    int i0 = c0 + t * 4;
    int s = 0;
    #pragma unroll
    for (int j = 0; j < 4; j++)
        if (i0 + j < n) s += deg[i0 + j];
    sh[t] = s;
    __syncthreads();
    for (int off = 128; off > 0; off >>= 1) {
        if (t < off) sh[t] += sh[t + off];
        __syncthreads();
    }
    if (t == 0) csum[blockIdx.x] = sh[0];
}

// exclusive scan of chunk sums (nchunks <= 128), single block of 128
__global__ void k_scan_csum(int* __restrict__ csum, int nchunks) {
    __shared__ int sh[128];
    int t = threadIdx.x;
    int v = (t < nchunks) ? csum[t] : 0;
    sh[t] = v;
    __syncthreads();
    for (int off = 1; off < 128; off <<= 1) {
        int nv = sh[t] + ((t >= off) ? sh[t - off] : 0);
        __syncthreads();
        sh[t] = nv;
        __syncthreads();
    }
    if (t < nchunks) csum[t] = sh[t] - v;   // exclusive
}

// ptr[i] = global exclusive prefix of deg
__global__ void k_scan_final(const int* __restrict__ deg,
                             const int* __restrict__ csum,
                             int* __restrict__ ptr, int n) {
    __shared__ int sh[256];
    int c0 = blockIdx.x * CHUNK;
    int t = threadIdx.x;
    int i0 = c0 + t * 4;
    int d0 = (i0 + 0 < n) ? deg[i0 + 0] : 0;
    int d1 = (i0 + 1 < n) ? deg[i0 + 1] : 0;
    int d2 = (i0 + 2 < n) ? deg[i0 + 2] : 0;
    int d3 = (i0 + 3 < n) ? deg[i0 + 3] : 0;
    int tot = d0 + d1 + d2 + d3;
    sh[t] = tot;
    __syncthreads();
    for (int off = 1; off < 256; off <<= 1) {
        int nv = sh[t] + ((t >= off) ? sh[t - off] : 0);
        __syncthreads();
        sh[t] = nv;
        __syncthreads();
    }
    int base = csum[blockIdx.x] + sh[t] - tot;  // exclusive across block
    if (i0 + 0 < n) ptr[i0 + 0] = base;
    if (i0 + 1 < n) ptr[i0 + 1] = base + d0;
    if (i0 + 2 < n) ptr[i0 + 2] = base + d0 + d1;
    if (i0 + 3 < n) ptr[i0 + 3] = base + d0 + d1 + d2;
}

// fill csr; afterwards ptr[i] = end offset of node i (= start of node i+1)
__global__ void k_fill(const int* __restrict__ src, const int* __restrict__ dst,
                       int* __restrict__ ptr, int* __restrict__ csr, int E) {
    int e = blockIdx.x * blockDim.x + threadIdx.x;
    if (e >= E) return;
    int pos = atomicAdd(&ptr[dst[e]], 1);
    csr[pos] = src[e];
}

// ---------------- gathers (atomic-free segment sum) ----------------

// agg[node][f] = sum over in-edges of t[src][f]; 32 lanes per node
__global__ void k_gather32(const float* __restrict__ t,
                           const int* __restrict__ csr,
                           const int* __restrict__ ptr,
                           float* __restrict__ agg, int n) {
    int tid = blockIdx.x * blockDim.x + threadIdx.x;
    int node = tid >> 5;
    int f = tid & 31;
    if (node >= n) return;
    int start = node ? ptr[node - 1] : 0;
    int end = ptr[node];
    float acc = 0.f;
    int j = start;
    for (; j + 1 < end; j += 2) {
        int s0 = csr[j], s1 = csr[j + 1];
        float v0 = t[(long long)s0 * HIDDEN + f];
        float v1 = t[(long long)s1 * HIDDEN + f];
        acc += v0;
        acc += v1;
    }
    if (j < end) acc += t[(long long)csr[j] * HIDDEN + f];
    agg[(long long)node * HIDDEN + f] = acc;
}

// h3[node] = (sum over in-edges of t3[src]) + b3, written to d_out
__global__ void k_gather2_out(const float* __restrict__ t3,
                              const int* __restrict__ csr,
                              const int* __restrict__ ptr,
                              const float* __restrict__ b3,
                              float* __restrict__ out, int n) {
    int node = blockIdx.x * blockDim.x + threadIdx.x;
    if (node >= n) return;
    int start = node ? ptr[node - 1] : 0;
    int end = ptr[node];
    float a0 = 0.f, a1 = 0.f;
    for (int j = start; j < end; j++) {
        int s = csr[j];
        float2 v = *reinterpret_cast<const float2*>(t3 + (long long)s * 2);
        a0 += v.x;
        a1 += v.y;
    }
    float2* o = reinterpret_cast<float2*>(out + (long long)node * 2);
    *o = make_float2(a0 + b3[0], a1 + b3[1]);
}

// ---------------- graph embedding + prediction ----------------

__global__ void k_bounds(const int* __restrict__ gids, int n, int* __restrict__ start) {
    int g = threadIdx.x;
    if (g > N_GRAPHS) return;
    int lo = 0, hi = n;
    while (lo < hi) {
        int mid = (lo + hi) >> 1;
        if (gids[mid] < g) lo = mid + 1; else hi = mid;
    }
    start[g] = lo;
}

__global__ void k_gsum(const float* __restrict__ nf,
                       const int* __restrict__ start,
                       float* __restrict__ ge) {
    int g = blockIdx.x;
    int s = start[g], e = start[g + 1];
    int f = threadIdx.x & 63;
    int sub = threadIdx.x >> 6;  // 0..3
    float acc = 0.f;
    for (int i = s + sub; i < e; i += 4)
        acc += nf[(long long)i * IN_FEATS + f];
    __shared__ float red[256];
    red[threadIdx.x] = acc;
    __syncthreads();
    if (threadIdx.x < 64) {
        float v = red[threadIdx.x] + red[threadIdx.x + 64] +
                  red[threadIdx.x + 128] + red[threadIdx.x + 192];
        float cnt = (float)(e - s);
        ge[g * IN_FEATS + threadIdx.x] = v / fmaxf(cnt, 1.0f);
    }
}

__global__ void k_pred(const float* __restrict__ ge,
                       const float* __restrict__ Wl,
                       const float* __restrict__ bl,
                       float* __restrict__ out) {
    int g = threadIdx.x;
    if (g >= N_GRAPHS) return;
    float acc = bl[0];
    for (int k = 0; k < IN_FEATS; k++)
        acc += ge[g * IN_FEATS + k] * Wl[k];
    out[g] = 1.f / (1.f + expf(-acc));
}

extern "C" void kernel_launch(void* const* d_in, const int* in_sizes, int n_in,
                              void* d_out, int out_size, void* d_ws, size_t ws_size,
                              hipStream_t stream) {
    const float* nf = (const float*)d_in[0];   // node_feats f32 [N,64]
    const float* W1 = (const float*)d_in[2];   // [64,32]
    const float* b1 = (const float*)d_in[3];   // [32]
    const float* W2 = (const float*)d_in[4];   // [32,32]
    const float* b2 = (const float*)d_in[5];   // [32]
    const float* W3 = (const float*)d_in[6];   // [32,2]
    const float* b3 = (const float*)d_in[7];   // [2]
    const float* Wl = (const float*)d_in[8];   // [64,1]
    const float* bl = (const float*)d_in[9];   // [1]
    const int* src  = (const int*)d_in[10];
    const int* dst  = (const int*)d_in[11];
    const int* gids = (const int*)d_in[12];

    const int N = in_sizes[0] / IN_FEATS;     // 100000
    const int E = in_sizes[10];               // 1600000

    float* out = (float*)d_out;

    // workspace layout: 2*N*32 f32 (25.6MB) + 2*N int (0.8MB) + E int (6.4MB) + small
    float* bufA = (float*)d_ws;               // t   [N,32]  (also aliased as t3 [N,2] in layer 3)
    float* bufB = bufA + (size_t)N * HIDDEN;  // agg [N,32]
    int* deg  = (int*)(bufB + (size_t)N * HIDDEN); // [N]
    int* ptr  = deg + N;                      // [N]
    int* csr  = ptr + N;                      // [E]
    int* csum = csr + E;                      // [<=128]
    float* ge = (float*)(csum + 128);         // [64,64]
    int* gstart = (int*)(ge + N_GRAPHS * IN_FEATS); // [65]

    const int TB = 256;
    int nodeBlocks = (N + TB - 1) / TB;
    int edgeBlocks = (E + TB - 1) / TB;
    int nchunks = (N + CHUNK - 1) / CHUNK;    // 98 for N=100000
    int g32Blocks = (N * 32 + TB - 1) / TB;

    // ---- CSR build (once, reused for all 3 layers) ----
    hipMemsetAsync(deg, 0, (size_t)N * sizeof(int), stream);
    k_deg<<<edgeBlocks, TB, 0, stream>>>(dst, deg, E);
    k_chunksum<<<nchunks, 256, 0, stream>>>(deg, csum, N);
    k_scan_csum<<<1, 128, 0, stream>>>(csum, nchunks);
    k_scan_final<<<nchunks, 256, 0, stream>>>(deg, csum, ptr, N);
    k_fill<<<edgeBlocks, TB, 0, stream>>>(src, dst, ptr, csr, E);
    // after k_fill: ptr[i] = end offset of node i

    // ---- layer 1 ----
    k_lin1<<<nodeBlocks, TB, 0, stream>>>(nf, W1, bufA, N);
    k_gather32<<<g32Blocks, TB, 0, stream>>>(bufA, csr, ptr, bufB, N);

    // ---- layer 2 ----
    k_lin2<<<nodeBlocks, TB, 0, stream>>>(bufB, b1, W2, bufA, N);
    k_gather32<<<g32Blocks, TB, 0, stream>>>(bufA, csr, ptr, bufB, N);

    // ---- layer 3 (t3 aliases bufA; gather fused with bias into d_out) ----
    k_lin3<<<nodeBlocks, TB, 0, stream>>>(bufB, b2, W3, bufA, N);
    k_gather2_out<<<nodeBlocks, TB, 0, stream>>>(bufA, csr, ptr, b3, out + N_GRAPHS, N);

    // ---- graph embedding + prediction ----
    k_bounds<<<1, 128, 0, stream>>>(gids, N, gstart);
    k_gsum<<<N_GRAPHS, 256, 0, stream>>>(nf, gstart, ge);
    k_pred<<<1, 64, 0, stream>>>(ge, Wl, bl, out);
}